// Round 3
// baseline (92.079 us; speedup 1.0000x reference)
//
#include <hip/hip_runtime.h>

#define N_ATT    2048
#define B_ROWS   32
#define THREADS  256
#define R_I      4                         // i-values per thread (register-blocked)
#define ICHUNK   (THREADS * R_I)           // 1024
#define ISPLITS  (N_ATT / ICHUNK)          // 2
#define JCHUNK   128
#define JSPLITS  (N_ATT / JCHUNK)          // 16
#define NBLOCKS  (B_ROWS * ISPLITS * JSPLITS)  // 1024
#define C_CLS    10
#define BETA     0.5f
#define EPS_ATT  1e-6f

// Fused: per-(row, i-chunk, j-chunk) partial Gini; last block to arrive
// (device-scope atomic counter) does the CE + final combine. Deterministic:
// the final sum is over all 1024 partials in a fixed order, regardless of
// which block finishes last.
__global__ __launch_bounds__(THREADS)
void satgini_fused(const float* __restrict__ att, const float* __restrict__ logits,
                   const int* __restrict__ labels, float* __restrict__ partials,
                   unsigned int* __restrict__ counter, float* __restrict__ out) {
    __shared__ float xs[JCHUNK];
    const int b      = blockIdx.x;
    const int row    = b >> 5;             // 32 blocks per row
    const int sub    = b & 31;
    const int isplit = sub >> 4;           // 0..1
    const int jsplit = sub & 15;           // 0..15
    const int t      = threadIdx.x;
    const float* a   = att + row * N_ATT;

    // stage j-chunk (128 floats) into LDS as log(att+eps)
    if (t < JCHUNK) xs[t] = logf(a[jsplit * JCHUNK + t] + EPS_ATT);

    // 4 register-resident xi per thread (coalesced loads)
    float xi[R_I];
#pragma unroll
    for (int k = 0; k < R_I; ++k)
        xi[k] = logf(a[isplit * ICHUNK + k * THREADS + t] + EPS_ATT);
    __syncthreads();

    // each ds_read_b128 (broadcast, conflict-free) feeds 4 i x 4 j = 32 VALU ops
    float acc[R_I] = {0.f, 0.f, 0.f, 0.f};
    const float4* xs4 = reinterpret_cast<const float4*>(xs);
#pragma unroll
    for (int j = 0; j < JCHUNK / 4; ++j) {
        const float4 v = xs4[j];
#pragma unroll
        for (int k = 0; k < R_I; ++k) {
            acc[k] += fabsf(xi[k] - v.x);
            acc[k] += fabsf(xi[k] - v.y);
            acc[k] += fabsf(xi[k] - v.z);
            acc[k] += fabsf(xi[k] - v.w);
        }
    }
    float s = (acc[0] + acc[1]) + (acc[2] + acc[3]);

    // block reduce (wave = 64)
#pragma unroll
    for (int off = 32; off > 0; off >>= 1) s += __shfl_down(s, off);
    __shared__ float wsum[THREADS / 64];
    const int lane = t & 63, wid = t >> 6;
    if (lane == 0) wsum[wid] = s;
    __syncthreads();
    if (t == 0) {
        float tot = 0.f;
#pragma unroll
        for (int w = 0; w < THREADS / 64; ++w) tot += wsum[w];
        partials[b] = tot;
    }

    // arrival: last block finalizes
    __shared__ unsigned int is_last;
    __threadfence();                       // make partials[b] device-visible
    if (t == 0) {
        const unsigned int prev = atomicAdd(counter, 1u);
        is_last = (prev == NBLOCKS - 1) ? 1u : 0u;
    }
    __syncthreads();
    if (!is_last) return;

    __threadfence();                       // acquire: see all partials
    volatile const float* pv = partials;
    float g = pv[t] + pv[t + 256] + pv[t + 512] + pv[t + 768];

    float ce = 0.f;
    if (t < B_ROWS) {
        const float* lg = logits + t * C_CLS;
        float m = lg[0];
#pragma unroll
        for (int c = 1; c < C_CLS; ++c) m = fmaxf(m, lg[c]);
        float sum = 0.f;
#pragma unroll
        for (int c = 0; c < C_CLS; ++c) sum += expf(lg[c] - m);
        ce = m + logf(sum) - lg[labels[t]];   // -log_softmax[label]
    }

    float cs = ce, gs = g;
#pragma unroll
    for (int off = 32; off > 0; off >>= 1) {
        cs += __shfl_down(cs, off);
        gs += __shfl_down(gs, off);
    }
    __shared__ float sc[THREADS / 64], sg[THREADS / 64];
    if (lane == 0) { sc[wid] = cs; sg[wid] = gs; }
    __syncthreads();
    if (t == 0) {
        float ce_tot = 0.f, g_tot = 0.f;
#pragma unroll
        for (int w = 0; w < THREADS / 64; ++w) { ce_tot += sc[w]; g_tot += sg[w]; }
        const float pred = ce_tot / (float)B_ROWS;
        const float info = g_tot / (2.0f * (float)N_ATT * (float)N_ATT + 1e-9f);
        out[0] = pred - BETA * info;
    }
}

extern "C" void kernel_launch(void* const* d_in, const int* in_sizes, int n_in,
                              void* d_out, int out_size, void* d_ws, size_t ws_size,
                              hipStream_t stream) {
    const float* att    = (const float*)d_in[0];   // [32, 2048] f32
    const float* logits = (const float*)d_in[1];   // [32, 10]   f32
    const int*   labels = (const int*)d_in[2];     // [32]       i32
    float* out = (float*)d_out;                    // scalar f32

    unsigned int* counter = (unsigned int*)d_ws;               // 4 B
    float* partials = (float*)d_ws + 64;                       // 1024 floats @ +256 B

    hipMemsetAsync(counter, 0, sizeof(unsigned int), stream);  // graph memset node
    satgini_fused<<<NBLOCKS, THREADS, 0, stream>>>(att, logits, labels,
                                                   partials, counter, out);
}

// Round 4
// 13.614 us; speedup vs baseline: 6.7637x; 6.7637x over previous
//
#include <hip/hip_runtime.h>

#define N_ATT    2048
#define B_ROWS   32
#define THREADS  256
#define R_I      4                         // i-values per thread (register-blocked)
#define ICHUNK   (THREADS * R_I)           // 1024
#define ISPLITS  (N_ATT / ICHUNK)          // 2
#define JCHUNK   128
#define JSPLITS  (N_ATT / JCHUNK)          // 16
#define NBLOCKS  (B_ROWS * ISPLITS * JSPLITS)  // 1024
#define C_CLS    10
#define BETA     0.5f
#define EPS_ATT  1e-6f

// Kernel 1: per-(row, i-chunk, j-chunk) partial Gini sums.
// 1024 blocks (4/CU, 4 waves/SIMD). Each thread holds 4 register-resident
// xi; each uniform-address ds_read_b128 feeds 4x4=32 VALU ops.
__global__ __launch_bounds__(THREADS)
void gini_partial(const float* __restrict__ att, float* __restrict__ ws) {
    __shared__ float xs[JCHUNK];
    const int b      = blockIdx.x;
    const int row    = b >> 5;             // 32 blocks per row
    const int sub    = b & 31;
    const int isplit = sub >> 4;           // 0..1
    const int jsplit = sub & 15;           // 0..15
    const int t      = threadIdx.x;
    const float* a   = att + row * N_ATT;

    // stage j-chunk (128 floats) into LDS as log(att+eps)
    if (t < JCHUNK) xs[t] = logf(a[jsplit * JCHUNK + t] + EPS_ATT);

    // 4 register-resident xi per thread (coalesced loads)
    float xi[R_I];
#pragma unroll
    for (int k = 0; k < R_I; ++k)
        xi[k] = logf(a[isplit * ICHUNK + k * THREADS + t] + EPS_ATT);
    __syncthreads();

    float acc[R_I] = {0.f, 0.f, 0.f, 0.f};
    const float4* xs4 = reinterpret_cast<const float4*>(xs);
#pragma unroll
    for (int j = 0; j < JCHUNK / 4; ++j) {
        const float4 v = xs4[j];
#pragma unroll
        for (int k = 0; k < R_I; ++k) {
            acc[k] += fabsf(xi[k] - v.x);
            acc[k] += fabsf(xi[k] - v.y);
            acc[k] += fabsf(xi[k] - v.z);
            acc[k] += fabsf(xi[k] - v.w);
        }
    }
    float s = (acc[0] + acc[1]) + (acc[2] + acc[3]);

    // block reduce (wave = 64)
#pragma unroll
    for (int off = 32; off > 0; off >>= 1) s += __shfl_down(s, off);
    __shared__ float wsum[THREADS / 64];
    const int lane = t & 63, wid = t >> 6;
    if (lane == 0) wsum[wid] = s;
    __syncthreads();
    if (t == 0) {
        float tot = 0.f;
#pragma unroll
        for (int w = 0; w < THREADS / 64; ++w) tot += wsum[w];
        ws[b] = tot;
    }
}

// Kernel 2: cross-entropy + combine. One block of 256 threads.
__global__ __launch_bounds__(THREADS)
void finalize(const float* __restrict__ logits, const int* __restrict__ labels,
              const float* __restrict__ ws, float* __restrict__ out) {
    const int t = threadIdx.x;

    float ce = 0.f;
    if (t < B_ROWS) {
        const float* lg = logits + t * C_CLS;
        float m = lg[0];
#pragma unroll
        for (int c = 1; c < C_CLS; ++c) m = fmaxf(m, lg[c]);
        float sum = 0.f;
#pragma unroll
        for (int c = 0; c < C_CLS; ++c) sum += expf(lg[c] - m);
        ce = m + logf(sum) - lg[labels[t]];   // -log_softmax[label]
    }

    // 1024 partials, 4 per thread (fixed order -> deterministic)
    float g = ws[t] + ws[t + 256] + ws[t + 512] + ws[t + 768];

    float cs = ce, gs = g;
#pragma unroll
    for (int off = 32; off > 0; off >>= 1) {
        cs += __shfl_down(cs, off);
        gs += __shfl_down(gs, off);
    }
    __shared__ float sc[THREADS / 64], sg[THREADS / 64];
    const int lane = t & 63, wid = t >> 6;
    if (lane == 0) { sc[wid] = cs; sg[wid] = gs; }
    __syncthreads();
    if (t == 0) {
        float ce_tot = 0.f, g_tot = 0.f;
#pragma unroll
        for (int w = 0; w < THREADS / 64; ++w) { ce_tot += sc[w]; g_tot += sg[w]; }
        const float pred = ce_tot / (float)B_ROWS;
        const float info = g_tot / (2.0f * (float)N_ATT * (float)N_ATT + 1e-9f);
        out[0] = pred - BETA * info;
    }
}

extern "C" void kernel_launch(void* const* d_in, const int* in_sizes, int n_in,
                              void* d_out, int out_size, void* d_ws, size_t ws_size,
                              hipStream_t stream) {
    const float* att    = (const float*)d_in[0];   // [32, 2048] f32
    const float* logits = (const float*)d_in[1];   // [32, 10]   f32
    const int*   labels = (const int*)d_in[2];     // [32]       i32
    float* out = (float*)d_out;                    // scalar f32
    float* ws  = (float*)d_ws;                     // 1024 floats of scratch

    gini_partial<<<NBLOCKS, THREADS, 0, stream>>>(att, ws);
    finalize<<<1, THREADS, 0, stream>>>(logits, labels, ws, out);
}